// Round 3
// baseline (363.948 us; speedup 1.0000x reference)
//
#include <hip/hip_runtime.h>

#define TSEQ 4096
#define CDIM 1024
#define DHEAD 64

typedef __bf16 bf16x8 __attribute__((ext_vector_type(8)));
typedef float f32x4 __attribute__((ext_vector_type(4)));

// load 8 consecutive floats, round to bf16 fragment
__device__ __forceinline__ bf16x8 load_cvt8(const float* __restrict__ p) {
  f32x4 lo = *(const f32x4*)p;
  f32x4 hi = *(const f32x4*)(p + 4);
  bf16x8 r;
  r[0] = (__bf16)lo[0]; r[1] = (__bf16)lo[1];
  r[2] = (__bf16)lo[2]; r[3] = (__bf16)lo[3];
  r[4] = (__bf16)hi[0]; r[5] = (__bf16)hi[1];
  r[6] = (__bf16)hi[2]; r[7] = (__bf16)hi[3];
  return r;
}

// ---------------- Projection: out[m,n] = sum_c emb[m,c] * W[n,c] ----------------
// Inputs are FLOAT32 (reference dtype); converted to bf16 in-register for MFMA.
// grid.x = M/64 (4 waves x 16 rows), grid.y = 3 (q,k,v). Q,K stored [B*T,64] bf16,
// V stored transposed Vt[b][64][T] bf16 so attention PV B-frags are contiguous.
__global__ __launch_bounds__(256) void proj_kernel(
    const float* __restrict__ qe, const float* __restrict__ ke,
    const float* __restrict__ ve, const float* __restrict__ wq,
    const float* __restrict__ wk, const float* __restrict__ wv,
    __bf16* __restrict__ Qo, __bf16* __restrict__ Ko, __bf16* __restrict__ Vto)
{
  const int pid = blockIdx.y;
  const float* __restrict__ emb = (pid == 0) ? qe : ((pid == 1) ? ke : ve);
  const float* __restrict__ W   = (pid == 0) ? wq : ((pid == 1) ? wk : wv);
  const int wave = threadIdx.x >> 6;
  const int lane = threadIdx.x & 63;
  const int g = lane >> 4, c = lane & 15;
  const int m0 = blockIdx.x * 64 + wave * 16;

  f32x4 acc[4];
#pragma unroll
  for (int n = 0; n < 4; ++n) acc[n] = (f32x4){0.f, 0.f, 0.f, 0.f};

  const float* ap = emb + (size_t)(m0 + c) * CDIM + g * 8;
  const float* wp = W + (size_t)c * CDIM + g * 8;

#pragma unroll 2
  for (int kk = 0; kk < CDIM; kk += 32) {
    bf16x8 a = load_cvt8(ap + kk);
#pragma unroll
    for (int n = 0; n < 4; ++n) {
      bf16x8 bw = load_cvt8(wp + (size_t)n * 16 * CDIM + kk);
      acc[n] = __builtin_amdgcn_mfma_f32_16x16x32_bf16(a, bw, acc[n], 0, 0, 0);
    }
  }

  // C/D layout: col = lane&15 (=c -> n*16+c), row = (lane>>4)*4 + reg (= m0+4g+r)
  if (pid < 2) {
    __bf16* __restrict__ dst = (pid == 0) ? Qo : Ko;
#pragma unroll
    for (int n = 0; n < 4; ++n)
#pragma unroll
      for (int r = 0; r < 4; ++r)
        dst[(size_t)(m0 + g * 4 + r) * DHEAD + n * 16 + c] = (__bf16)acc[n][r];
  } else {
    // Vt[b][v][t]: regs 0..3 are 4 consecutive t -> pack one 8B store
    const int t0 = m0 + g * 4;
    const int bb = t0 >> 12;        // 4096 rows per batch, blocks never straddle
    const int tl = t0 & (TSEQ - 1);
#pragma unroll
    for (int n = 0; n < 4; ++n) {
      const int v = n * 16 + c;
      ushort4 pk;
      pk.x = __builtin_bit_cast(unsigned short, (__bf16)acc[n][0]);
      pk.y = __builtin_bit_cast(unsigned short, (__bf16)acc[n][1]);
      pk.z = __builtin_bit_cast(unsigned short, (__bf16)acc[n][2]);
      pk.w = __builtin_bit_cast(unsigned short, (__bf16)acc[n][3]);
      *(ushort4*)(Vto + ((size_t)bb * DHEAD + v) * TSEQ + tl) = pk;
    }
  }
}

// ---------------- Causal flash attention, static-max softmax ----------------
// One block = 16 q-rows, 2 waves split the s-tiles (st = wave, wave+2, ...).
// Static m=0 is safe: |scores| < ~1 after 1/32 scale, exp2 cannot overflow.
// Row-sum l computed with a ones-vector MFMA (lands in same C-layout rows as O).
// OUTPUT IS FLOAT32 (reference output dtype).
__global__ __launch_bounds__(128) void attn_kernel(
    const __bf16* __restrict__ Q, const __bf16* __restrict__ K,
    const __bf16* __restrict__ Vt, float* __restrict__ out)
{
  __shared__ __bf16 Plds[2][16][72];   // per-wave P (C-layout -> A-layout round trip)
  __shared__ float Om[2][16][65];      // per-wave partial O for the merge
  __shared__ float La[2][16];          // per-wave partial row-sums

  const int b = blockIdx.y;
  const int tile = (int)gridDim.x - 1 - (int)blockIdx.x;  // big tiles first
  const int q0 = tile * 16;
  const int wave = threadIdx.x >> 6;
  const int lane = threadIdx.x & 63;
  const int g = lane >> 4, c = lane & 15;

  const __bf16* Qb = Q + (size_t)b * TSEQ * DHEAD;
  const __bf16* Kb = K + (size_t)b * TSEQ * DHEAD;
  const __bf16* Vb = Vt + (size_t)b * DHEAD * TSEQ;

  bf16x8 aq0 = *(const bf16x8*)(Qb + (size_t)(q0 + c) * DHEAD + g * 8);
  bf16x8 aq1 = *(const bf16x8*)(Qb + (size_t)(q0 + c) * DHEAD + 32 + g * 8);

  bf16x8 ones;
#pragma unroll
  for (int j = 0; j < 8; ++j) ones[j] = (__bf16)1.0f;

  f32x4 o[4];
#pragma unroll
  for (int n = 0; n < 4; ++n) o[n] = (f32x4){0.f, 0.f, 0.f, 0.f};
  f32x4 lacc = (f32x4){0.f, 0.f, 0.f, 0.f};

  const float kScale = 0.04508422f;  // (1/32) * log2(e)
  const int nt = (q0 + 16 + 63) >> 6;

  for (int st = wave; st < nt; st += 2) {
    const int s0 = st * 64;
    // S = Q K^T  (16 q x 64 s per wave)
    f32x4 s[4];
#pragma unroll
    for (int n = 0; n < 4; ++n) {
      const __bf16* kp = Kb + (size_t)(s0 + n * 16 + c) * DHEAD + g * 8;
      bf16x8 b0 = *(const bf16x8*)(kp);
      bf16x8 b1 = *(const bf16x8*)(kp + 32);
      f32x4 z = (f32x4){0.f, 0.f, 0.f, 0.f};
      z = __builtin_amdgcn_mfma_f32_16x16x32_bf16(aq0, b0, z, 0, 0, 0);
      s[n] = __builtin_amdgcn_mfma_f32_16x16x32_bf16(aq1, b1, z, 0, 0, 0);
    }
    // mask + exp2 (static max), write P to LDS in [q][s] layout
#pragma unroll
    for (int n = 0; n < 4; ++n) {
      const int sidx = s0 + n * 16 + c;
#pragma unroll
      for (int r = 0; r < 4; ++r) {
        const int qidx = q0 + g * 4 + r;
        float p = (sidx <= qidx) ? __builtin_amdgcn_exp2f(s[n][r] * kScale) : 0.f;
        Plds[wave][g * 4 + r][n * 16 + c] = (__bf16)p;
      }
    }
    // A-frags of P: lane reads row c, 8 contiguous s per k-chunk.
    // Same-wave DS ops are processed in order; compiler handles lgkmcnt.
    bf16x8 p0 = *(const bf16x8*)(&Plds[wave][c][g * 8]);
    bf16x8 p1 = *(const bf16x8*)(&Plds[wave][c][32 + g * 8]);
    // l += rowsum(P) via ones MFMA (result rows match O accumulator rows)
    lacc = __builtin_amdgcn_mfma_f32_16x16x32_bf16(p0, ones, lacc, 0, 0, 0);
    lacc = __builtin_amdgcn_mfma_f32_16x16x32_bf16(p1, ones, lacc, 0, 0, 0);
    // O += P V  (Vt gives contiguous B-frags)
#pragma unroll
    for (int n = 0; n < 4; ++n) {
      const __bf16* vp = Vb + (size_t)(n * 16 + c) * TSEQ + s0 + g * 8;
      bf16x8 v0 = *(const bf16x8*)(vp);
      bf16x8 v1 = *(const bf16x8*)(vp + 32);
      o[n] = __builtin_amdgcn_mfma_f32_16x16x32_bf16(p0, v0, o[n], 0, 0, 0);
      o[n] = __builtin_amdgcn_mfma_f32_16x16x32_bf16(p1, v1, o[n], 0, 0, 0);
    }
  }

  // merge the two waves' partials (static max => plain sums)
#pragma unroll
  for (int n = 0; n < 4; ++n)
#pragma unroll
    for (int r = 0; r < 4; ++r)
      Om[wave][g * 4 + r][n * 16 + c] = o[n][r];
  if (c == 0) {
#pragma unroll
    for (int r = 0; r < 4; ++r) La[wave][g * 4 + r] = lacc[r];
  }
  __syncthreads();

  // f32 output: 128 threads x (1 row x 8 cols) = 16 rows x 64 cols
  const int tid = threadIdx.x;
  const int q = tid >> 3;
  const int v0 = (tid & 7) * 8;
  const float inv = 1.0f / (La[0][q] + La[1][q]);
  f32x4 r0, r1;
#pragma unroll
  for (int j = 0; j < 4; ++j) {
    r0[j] = (Om[0][q][v0 + j] + Om[1][q][v0 + j]) * inv;
    r1[j] = (Om[0][q][v0 + 4 + j] + Om[1][q][v0 + 4 + j]) * inv;
  }
  float* op = out + ((size_t)b * TSEQ + q0 + q) * DHEAD + v0;
  *(f32x4*)op = r0;
  *(f32x4*)(op + 4) = r1;
}

extern "C" void kernel_launch(void* const* d_in, const int* in_sizes, int n_in,
                              void* d_out, int out_size, void* d_ws, size_t ws_size,
                              hipStream_t stream) {
  const float* qe = (const float*)d_in[0];
  const float* ke = (const float*)d_in[1];
  const float* ve = (const float*)d_in[2];
  const float* wq = (const float*)d_in[3];
  const float* wk = (const float*)d_in[4];
  const float* wv = (const float*)d_in[5];

  __bf16* Qw  = (__bf16*)d_ws;
  __bf16* Kw  = Qw + (size_t)4 * TSEQ * DHEAD;
  __bf16* Vtw = Kw + (size_t)4 * TSEQ * DHEAD;

  dim3 g1(4 * TSEQ / 64, 3), b1(256);
  proj_kernel<<<g1, b1, 0, stream>>>(qe, ke, ve, wq, wk, wv, Qw, Kw, Vtw);

  dim3 g2(TSEQ / 16, 4), b2(128);
  attn_kernel<<<g2, b2, 0, stream>>>(Qw, Kw, Vtw, (float*)d_out);
}

// Round 4
// 338.365 us; speedup vs baseline: 1.0756x; 1.0756x over previous
//
#include <hip/hip_runtime.h>

#define TSEQ 4096
#define CDIM 1024
#define DHEAD 64

typedef __bf16 bf16x8 __attribute__((ext_vector_type(8)));
typedef float f32x4 __attribute__((ext_vector_type(4)));

// ---------------- Projection: out[m,n] = sum_c emb[m,c] * W[n,c] ----------------
// LDS-staged: per 128-col K-chunk, stage emb tile (64 rows) and the full W slice
// (64 rows) as bf16 via row-contiguous 1KB global loads (fixes the 4KB-stride
// fragment-pattern loads + W re-read that made v2 latency-bound at 123us).
// grid.x = M/64, grid.y = 3 (q,k,v). Q,K stored [B*T,64] bf16,
// V stored transposed Vt[b][64][T] bf16 so attention PV B-frags are contiguous.
#define KCHUNK 128          // f32 cols per chunk
#define NCHUNK (CDIM / KCHUNK)
#define LSTRIDE 136         // 128 + 8 pad (keeps 16B alignment: 272B = 17*16)

__global__ __launch_bounds__(256) void proj_kernel(
    const float* __restrict__ qe, const float* __restrict__ ke,
    const float* __restrict__ ve, const float* __restrict__ wq,
    const float* __restrict__ wk, const float* __restrict__ wv,
    __bf16* __restrict__ Qo, __bf16* __restrict__ Ko, __bf16* __restrict__ Vto)
{
  __shared__ __bf16 Al[64][LSTRIDE];
  __shared__ __bf16 Wl[64][LSTRIDE];

  const int pid = blockIdx.y;
  const float* __restrict__ emb = (pid == 0) ? qe : ((pid == 1) ? ke : ve);
  const float* __restrict__ W   = (pid == 0) ? wq : ((pid == 1) ? wk : wv);
  const int wave = threadIdx.x >> 6;
  const int lane = threadIdx.x & 63;
  const int g = lane >> 4, c = lane & 15;
  const int bm0 = blockIdx.x * 64;

  const int lr = lane >> 5;          // row parity within a 2-row staging inst
  const int lc = (lane & 31) * 4;    // f32 col within chunk (also bf16 col)

  f32x4 acc[4];
#pragma unroll
  for (int n = 0; n < 4; ++n) acc[n] = (f32x4){0.f, 0.f, 0.f, 0.f};

  for (int ch = 0; ch < NCHUNK; ++ch) {
    const int k0 = ch * KCHUNK;
    __syncthreads();  // prior chunk's fragment reads done before overwrite
    // stage: each wave covers rows [wave*16, wave*16+16), 2 rows per inst
#pragma unroll
    for (int j = 0; j < 8; ++j) {
      const int row = wave * 16 + 2 * j + lr;
      f32x4 av = *(const f32x4*)(emb + (size_t)(bm0 + row) * CDIM + k0 + lc);
      f32x4 wv4 = *(const f32x4*)(W + (size_t)row * CDIM + k0 + lc);
      short4 pa, pw;
      pa.x = __builtin_bit_cast(short, (__bf16)av[0]);
      pa.y = __builtin_bit_cast(short, (__bf16)av[1]);
      pa.z = __builtin_bit_cast(short, (__bf16)av[2]);
      pa.w = __builtin_bit_cast(short, (__bf16)av[3]);
      pw.x = __builtin_bit_cast(short, (__bf16)wv4[0]);
      pw.y = __builtin_bit_cast(short, (__bf16)wv4[1]);
      pw.z = __builtin_bit_cast(short, (__bf16)wv4[2]);
      pw.w = __builtin_bit_cast(short, (__bf16)wv4[3]);
      *(short4*)&Al[row][lc] = pa;
      *(short4*)&Wl[row][lc] = pw;
    }
    __syncthreads();
    // compute: wave's A rows = [wave*16, +16); all 64 W rows
#pragma unroll
    for (int ks = 0; ks < KCHUNK / 32; ++ks) {
      bf16x8 af = *(const bf16x8*)&Al[wave * 16 + c][ks * 32 + g * 8];
#pragma unroll
      for (int n = 0; n < 4; ++n) {
        bf16x8 wf = *(const bf16x8*)&Wl[n * 16 + c][ks * 32 + g * 8];
        acc[n] = __builtin_amdgcn_mfma_f32_16x16x32_bf16(af, wf, acc[n], 0, 0, 0);
      }
    }
  }

  const int m0 = bm0 + wave * 16;
  // C/D layout: col = lane&15 (=c -> n*16+c), row = (lane>>4)*4 + reg (= m0+4g+r)
  if (pid < 2) {
    __bf16* __restrict__ dst = (pid == 0) ? Qo : Ko;
#pragma unroll
    for (int n = 0; n < 4; ++n)
#pragma unroll
      for (int r = 0; r < 4; ++r)
        dst[(size_t)(m0 + g * 4 + r) * DHEAD + n * 16 + c] = (__bf16)acc[n][r];
  } else {
    // Vt[b][v][t]: regs 0..3 are 4 consecutive t -> pack one 8B store
    const int t0 = m0 + g * 4;
    const int bb = t0 >> 12;        // 4096 rows per batch, blocks never straddle
    const int tl = t0 & (TSEQ - 1);
#pragma unroll
    for (int n = 0; n < 4; ++n) {
      const int v = n * 16 + c;
      ushort4 pk;
      pk.x = __builtin_bit_cast(unsigned short, (__bf16)acc[n][0]);
      pk.y = __builtin_bit_cast(unsigned short, (__bf16)acc[n][1]);
      pk.z = __builtin_bit_cast(unsigned short, (__bf16)acc[n][2]);
      pk.w = __builtin_bit_cast(unsigned short, (__bf16)acc[n][3]);
      *(ushort4*)(Vto + ((size_t)bb * DHEAD + v) * TSEQ + tl) = pk;
    }
  }
}

// ---------------- Causal flash attention, static-max softmax ----------------
// One block = 16 q-rows, 2 waves split the s-tiles (st = wave, wave+2, ...).
// Static m=0 is safe: |scores| < ~1 after 1/32 scale, exp2 cannot overflow.
// Row-sum l computed with a ones-vector MFMA (lands in same C-layout rows as O).
// OUTPUT IS FLOAT32 (reference output dtype).
__global__ __launch_bounds__(128) void attn_kernel(
    const __bf16* __restrict__ Q, const __bf16* __restrict__ K,
    const __bf16* __restrict__ Vt, float* __restrict__ out)
{
  __shared__ __bf16 Plds[2][16][72];   // per-wave P (C-layout -> A-layout round trip)
  __shared__ float Om[2][16][65];      // per-wave partial O for the merge
  __shared__ float La[2][16];          // per-wave partial row-sums

  const int b = blockIdx.y;
  const int tile = (int)gridDim.x - 1 - (int)blockIdx.x;  // big tiles first
  const int q0 = tile * 16;
  const int wave = threadIdx.x >> 6;
  const int lane = threadIdx.x & 63;
  const int g = lane >> 4, c = lane & 15;

  const __bf16* Qb = Q + (size_t)b * TSEQ * DHEAD;
  const __bf16* Kb = K + (size_t)b * TSEQ * DHEAD;
  const __bf16* Vb = Vt + (size_t)b * DHEAD * TSEQ;

  bf16x8 aq0 = *(const bf16x8*)(Qb + (size_t)(q0 + c) * DHEAD + g * 8);
  bf16x8 aq1 = *(const bf16x8*)(Qb + (size_t)(q0 + c) * DHEAD + 32 + g * 8);

  bf16x8 ones;
#pragma unroll
  for (int j = 0; j < 8; ++j) ones[j] = (__bf16)1.0f;

  f32x4 o[4];
#pragma unroll
  for (int n = 0; n < 4; ++n) o[n] = (f32x4){0.f, 0.f, 0.f, 0.f};
  f32x4 lacc = (f32x4){0.f, 0.f, 0.f, 0.f};

  const float kScale = 0.04508422f;  // (1/32) * log2(e)
  const int nt = (q0 + 16 + 63) >> 6;

  for (int st = wave; st < nt; st += 2) {
    const int s0 = st * 64;
    // S = Q K^T  (16 q x 64 s per wave)
    f32x4 s[4];
#pragma unroll
    for (int n = 0; n < 4; ++n) {
      const __bf16* kp = Kb + (size_t)(s0 + n * 16 + c) * DHEAD + g * 8;
      bf16x8 b0 = *(const bf16x8*)(kp);
      bf16x8 b1 = *(const bf16x8*)(kp + 32);
      f32x4 z = (f32x4){0.f, 0.f, 0.f, 0.f};
      z = __builtin_amdgcn_mfma_f32_16x16x32_bf16(aq0, b0, z, 0, 0, 0);
      s[n] = __builtin_amdgcn_mfma_f32_16x16x32_bf16(aq1, b1, z, 0, 0, 0);
    }
    // mask + exp2 (static max), write P to LDS in [q][s] layout
#pragma unroll
    for (int n = 0; n < 4; ++n) {
      const int sidx = s0 + n * 16 + c;
#pragma unroll
      for (int r = 0; r < 4; ++r) {
        const int qidx = q0 + g * 4 + r;
        float p = (sidx <= qidx) ? __builtin_amdgcn_exp2f(s[n][r] * kScale) : 0.f;
        Plds[wave][g * 4 + r][n * 16 + c] = (__bf16)p;
      }
    }
    // A-frags of P: lane reads row c, 8 contiguous s per k-chunk.
    // Same-wave DS ops are processed in order; compiler handles lgkmcnt.
    bf16x8 p0 = *(const bf16x8*)(&Plds[wave][c][g * 8]);
    bf16x8 p1 = *(const bf16x8*)(&Plds[wave][c][32 + g * 8]);
    // l += rowsum(P) via ones MFMA (result rows match O accumulator rows)
    lacc = __builtin_amdgcn_mfma_f32_16x16x32_bf16(p0, ones, lacc, 0, 0, 0);
    lacc = __builtin_amdgcn_mfma_f32_16x16x32_bf16(p1, ones, lacc, 0, 0, 0);
    // O += P V  (Vt gives contiguous B-frags)
#pragma unroll
    for (int n = 0; n < 4; ++n) {
      const __bf16* vp = Vb + (size_t)(n * 16 + c) * TSEQ + s0 + g * 8;
      bf16x8 v0 = *(const bf16x8*)(vp);
      bf16x8 v1 = *(const bf16x8*)(vp + 32);
      o[n] = __builtin_amdgcn_mfma_f32_16x16x32_bf16(p0, v0, o[n], 0, 0, 0);
      o[n] = __builtin_amdgcn_mfma_f32_16x16x32_bf16(p1, v1, o[n], 0, 0, 0);
    }
  }

  // merge the two waves' partials (static max => plain sums)
#pragma unroll
  for (int n = 0; n < 4; ++n)
#pragma unroll
    for (int r = 0; r < 4; ++r)
      Om[wave][g * 4 + r][n * 16 + c] = o[n][r];
  if (c == 0) {
#pragma unroll
    for (int r = 0; r < 4; ++r) La[wave][g * 4 + r] = lacc[r];
  }
  __syncthreads();

  // f32 output: 128 threads x (1 row x 8 cols) = 16 rows x 64 cols
  const int tid = threadIdx.x;
  const int q = tid >> 3;
  const int v0 = (tid & 7) * 8;
  const float inv = 1.0f / (La[0][q] + La[1][q]);
  f32x4 r0, r1;
#pragma unroll
  for (int j = 0; j < 4; ++j) {
    r0[j] = (Om[0][q][v0 + j] + Om[1][q][v0 + j]) * inv;
    r1[j] = (Om[0][q][v0 + 4 + j] + Om[1][q][v0 + 4 + j]) * inv;
  }
  float* op = out + ((size_t)b * TSEQ + q0 + q) * DHEAD + v0;
  *(f32x4*)op = r0;
  *(f32x4*)(op + 4) = r1;
}

extern "C" void kernel_launch(void* const* d_in, const int* in_sizes, int n_in,
                              void* d_out, int out_size, void* d_ws, size_t ws_size,
                              hipStream_t stream) {
  const float* qe = (const float*)d_in[0];
  const float* ke = (const float*)d_in[1];
  const float* ve = (const float*)d_in[2];
  const float* wq = (const float*)d_in[3];
  const float* wk = (const float*)d_in[4];
  const float* wv = (const float*)d_in[5];

  __bf16* Qw  = (__bf16*)d_ws;
  __bf16* Kw  = Qw + (size_t)4 * TSEQ * DHEAD;
  __bf16* Vtw = Kw + (size_t)4 * TSEQ * DHEAD;

  dim3 g1(4 * TSEQ / 64, 3), b1(256);
  proj_kernel<<<g1, b1, 0, stream>>>(qe, ke, ve, wq, wk, wv, Qw, Kw, Vtw);

  dim3 g2(TSEQ / 16, 4), b2(128);
  attn_kernel<<<g2, b2, 0, stream>>>(Qw, Kw, Vtw, (float*)d_out);
}